// Round 8
// baseline (362.774 us; speedup 1.0000x reference)
//
#include <hip/hip_runtime.h>

// B=8, T=2048, D_MODEL=1024, D_HEAD=64, fp32 in/out.
// pack  -> Wt bf16[192][1024] (+ zeroes the per-(b,qt) combine counters)
// gemm  -> qkvqk bf16[16384][128] (Q log2-scaled | K), vT bf16[8][64][2048]
//          (m97-style: global_load_lds staging, XOR-swizzled LDS, 2-barrier K-loop)
// attn  -> split-K no-max log2 flash (1152 packed jobs); LAST block per (b,qt)
//          (device-scope atomic counter) performs the combine inline.
#define TT   2048
#define DM   1024
#define DH   64
#define NB   8
#define KST  72    // k_lds / p_lds row stride (elems): 36 dwords = 4 mod 32 banks
#define VST  264   // v_lds row stride: 132 dwords = 4 mod 32 banks

typedef __attribute__((ext_vector_type(4))) float          f32x4;
typedef __attribute__((ext_vector_type(4))) int            i32x4;
typedef __attribute__((ext_vector_type(4))) unsigned short u16x4;
typedef __attribute__((ext_vector_type(8))) short          s16x8;  // bf16x8 frag (4 VGPRs)

__device__ __forceinline__ unsigned short f2bf(float f) {  // RNE fp32->bf16
  unsigned int u = __float_as_uint(f);
  u += 0x7fffu + ((u >> 16) & 1u);
  return (unsigned short)(u >> 16);
}

#define MFMA(acc, a, b) \
  (acc) = __builtin_amdgcn_mfma_f32_16x16x32_bf16((a), (b), (acc), 0, 0, 0)

// Async global->LDS DMA, 16B/lane. LDS dest is wave-uniform base + lane*16.
__device__ __forceinline__ void gload_lds16(const void* g, void* l) {
  __builtin_amdgcn_global_load_lds(
      (const __attribute__((address_space(1))) void*)g,
      (__attribute__((address_space(3))) void*)l, 16, 0, 0);
}

// ws layout (bytes)
#define WS_WT    0u
#define WS_QK    393216u     // 16384*128*2 = 4,194,304
#define WS_VT    4587520u    // 8*64*2048*2 = 2,097,152
#define WS_OP    6684672u    // 8*144*4096*2 = 9,437,184 (bf16 partial O)
#define WS_ML    16121856u   // 8*144*64*4  = 294,912   (f32 l per row)
#define WS_CNT   16416768u   // 8*32 int    = 1,024     (combine counters)

// ---------------- pack: W -> Wt bf16[192][1024]; zero combine counters ---------------
__global__ __launch_bounds__(256) void pack_w_kernel(
    const float* __restrict__ wq, const float* __restrict__ wk,
    const float* __restrict__ wv, unsigned short* __restrict__ wt,
    int* __restrict__ cnt) {
  int idx = blockIdx.x * 256 + threadIdx.x;
  if (blockIdx.x == 0 && threadIdx.x < NB * 32) cnt[threadIdx.x] = 0;
  if (idx >= 192 * DM) return;
  int n = idx >> 10;
  int k = idx & (DM - 1);
  const float* src = (n < 64) ? wq : ((n < 128) ? wk : wv);
  wt[(size_t)n * DM + k] = f2bf(src[(size_t)k * DH + (n & 63)]);
}

// ---------------- QKV GEMM (m97 structure, unchanged from R6) ------------------------
__global__ __launch_bounds__(256) void qkv_gemm_kernel(
    const float* __restrict__ x, const unsigned short* __restrict__ wt,
    unsigned short* __restrict__ qkvqk, unsigned short* __restrict__ vt) {
  __shared__ __align__(16) float          a_lds[32 * 64];    // 8 KB, swizzled chunks
  __shared__ __align__(16) unsigned short b_lds[192 * 64];   // 24 KB, swizzled chunks

  const int tid  = threadIdx.x;
  const int lane = tid & 63;
  const int w    = tid >> 6;
  const int ln   = lane & 15;
  const int quad = lane >> 4;
  const int mw   = w & 1;
  const int nw   = w >> 1;
  const int m0   = blockIdx.x * 32;
  const int n0   = nw * 96;
  const int lsw  = ln & 7;          // read-side swizzle key

  int agoff[2];
  #pragma unroll
  for (int i = 0; i < 2; ++i) {
    int s = i * 256 + w * 64 + lane;
    int m = s >> 4, cc = s & 15;                 // A: 16 chunks/row (16B = 4 fp32)
    agoff[i] = (m0 + m) * DM + ((cc ^ (m & 7)) << 2);
  }
  int bgoff[6];
  #pragma unroll
  for (int j = 0; j < 6; ++j) {
    int s = j * 256 + w * 64 + lane;
    int n = s >> 3, cc = s & 7;                  // B: 8 chunks/row (16B = 8 bf16)
    bgoff[j] = n * DM + ((cc ^ (n & 7)) << 3);
  }

  f32x4 acc[6];
  #pragma unroll
  for (int i = 0; i < 6; ++i) acc[i] = (f32x4){0.f, 0.f, 0.f, 0.f};
  union { s16x8 v; unsigned short h[8]; } ap;

  #pragma unroll
  for (int i = 0; i < 2; ++i)
    gload_lds16(x + agoff[i], (void*)(a_lds + (i * 256 + w * 64) * 4));
  #pragma unroll
  for (int j = 0; j < 6; ++j)
    gload_lds16(wt + bgoff[j], (void*)(b_lds + (j * 256 + w * 64) * 8));

  for (int k0 = 0; k0 < DM; k0 += 64) {
    __syncthreads();               // drains vmcnt(0): staged tile visible
    #pragma unroll
    for (int ks = 0; ks < 64; ks += 32) {
      const int m  = mw * 16 + ln;
      const int c0 = (ks >> 2) + 2 * quad;       // float-chunk of A fragment
      f32x4 v0 = *(const f32x4*)&a_lds[m * 64 + ((c0 ^ lsw) << 2)];
      f32x4 v1 = *(const f32x4*)&a_lds[m * 64 + (((c0 + 1) ^ lsw) << 2)];
      #pragma unroll
      for (int j = 0; j < 4; ++j) { ap.h[j] = f2bf(v0[j]); ap.h[4 + j] = f2bf(v1[j]); }
      s16x8 af = ap.v;
      const int cb = (ks >> 3) + quad;           // bf16-chunk of B fragment
      #pragma unroll
      for (int nt = 0; nt < 6; ++nt) {
        int n = n0 + nt * 16 + ln;
        s16x8 bf = *(const s16x8*)&b_lds[n * 64 + ((cb ^ lsw) << 3)];
        MFMA(acc[nt], af, bf);
      }
    }
    __syncthreads();               // all waves done reading before re-stage
    if (k0 + 64 < DM) {
      const int kn = k0 + 64;
      #pragma unroll
      for (int i = 0; i < 2; ++i)
        gload_lds16(x + agoff[i] + kn, (void*)(a_lds + (i * 256 + w * 64) * 4));
      #pragma unroll
      for (int j = 0; j < 6; ++j)
        gload_lds16(wt + bgoff[j] + kn, (void*)(b_lds + (j * 256 + w * 64) * 8));
    }
  }

  const float QS = 0.18033688011112042f;  // (1/8) * log2(e)
  const int mm0 = m0 + mw * 16;
  const int bz  = mm0 >> 11;
  const int tb  = (mm0 & 2047) + quad * 4;
  #pragma unroll
  for (int nt = 0; nt < 6; ++nt) {
    const int ncol = n0 + nt * 16 + ln;
    if (ncol < 128) {                     // Q (scaled) | K -> qkvqk
      const float sc = (ncol < 64) ? QS : 1.0f;
      #pragma unroll
      for (int r = 0; r < 4; ++r) {
        int row = mm0 + quad * 4 + r;     // C/D: row = quad*4+reg, col = lane&15
        qkvqk[(size_t)row * 128 + ncol] = f2bf(acc[nt][r] * sc);
      }
    } else {                              // V -> vT[b][d][t]
      int d = ncol - 128;
      u16x4 h;
      #pragma unroll
      for (int r = 0; r < 4; ++r) h[r] = f2bf(acc[nt][r]);
      *(u16x4*)(vt + ((size_t)bz * 64 + d) * TT + tb) = h;
    }
  }
}

// ---------------- attn partial + inline last-arriver combine -------------------------
// 1152 packed jobs; job = (bz, qt, c). After writing its partial, the LAST block for
// (bz,qt) (device-scope atomic counter) re-reads all chunk partials and combines.
__global__ __launch_bounds__(256) void attn_part_kernel(
    const unsigned short* __restrict__ qkvqk, const unsigned short* __restrict__ vt,
    unsigned short* __restrict__ opart, float* __restrict__ ml,
    int* __restrict__ cnt, float* __restrict__ out) {
  // decode blockIdx.x -> (bz, qt, c): group g holds 4 q-tiles x (g+1) chunks
  const int f  = blockIdx.x;
  const int bz = f / 144;
  const int rw = f - bz * 144;
  int g = 0;
  #pragma unroll
  for (int t = 1; t < 8; ++t) if (rw >= 2 * t * (t + 1)) g = t;
  const int rr = rw - 2 * g * (g + 1);
  const int dq = rr / (g + 1);
  const int qt = 4 * g + dq;
  const int c  = rr - dq * (g + 1);
  const int rq = qt & 3;
  const int ntiles = (c == g) ? (rq + 1) : 4;
  const int nch    = g + 1;

  __shared__ __align__(16) unsigned short k_lds[256 * KST];
  __shared__ __align__(16) unsigned short v_lds[64 * VST];
  __shared__ __align__(16) unsigned short p_lds[64 * KST];
  __shared__ int is_last;

  const int tid  = threadIdx.x;
  const int w    = tid >> 6;
  const int lane = tid & 63;
  const int ln   = lane & 15;
  const int quad = lane >> 4;
  const int bb   = bz * TT;
  const int kbase = c * 256;

  #pragma unroll
  for (int i = 0; i < 8; ++i) {
    int cid = i * 256 + tid;
    int row = cid >> 3, dc = (cid & 7) * 8;
    *(i32x4*)&k_lds[row * KST + dc] =
        *(const i32x4*)(qkvqk + (size_t)(bb + kbase + row) * 128 + 64 + dc);
  }
  #pragma unroll
  for (int i = 0; i < 8; ++i) {
    int cid = i * 256 + tid;
    int d = cid >> 5, tc = (cid & 31) * 8;
    *(i32x4*)&v_lds[d * VST + tc] =
        *(const i32x4*)(vt + ((size_t)bz * 64 + d) * TT + kbase + tc);
  }

  const unsigned short* qrow = qkvqk + (size_t)(bb + qt * 64 + w * 16 + ln) * 128;
  const s16x8 qf0 = *(const s16x8*)(qrow + quad * 8);
  const s16x8 qf1 = *(const s16x8*)(qrow + 32 + quad * 8);

  s16x8 ones;
  #pragma unroll
  for (int j = 0; j < 8; ++j) ones[j] = (short)0x3F80;  // bf16 1.0

  f32x4 acc_o[4], acc_l;
  #pragma unroll
  for (int i = 0; i < 4; ++i) acc_o[i] = (f32x4){0.f, 0.f, 0.f, 0.f};
  acc_l = (f32x4){0.f, 0.f, 0.f, 0.f};

  const int qg_base = qt * 64 + w * 16 + quad * 4;
  __syncthreads();  // staging complete

  for (int ct = 0; ct < ntiles; ++ct) {
    const int ktg = c * 4 + ct;
    const bool diag = (ktg == qt);

    f32x4 acc_s[4];
    #pragma unroll
    for (int i = 0; i < 4; ++i) acc_s[i] = (f32x4){0.f, 0.f, 0.f, 0.f};
    #pragma unroll
    for (int ns = 0; ns < 4; ++ns) {
      s16x8 kf0 = *(const s16x8*)&k_lds[(ct * 64 + ns * 16 + ln) * KST + quad * 8];
      s16x8 kf1 = *(const s16x8*)&k_lds[(ct * 64 + ns * 16 + ln) * KST + 32 + quad * 8];
      MFMA(acc_s[ns], qf0, kf0);
      MFMA(acc_s[ns], qf1, kf1);
    }

    #pragma unroll
    for (int r = 0; r < 4; ++r) {
      const int qg = qg_base + r;
      #pragma unroll
      for (int ns = 0; ns < 4; ++ns) {
        float s = acc_s[ns][r];
        if (diag) {
          int kg = ktg * 64 + ns * 16 + ln;
          s = (kg <= qg) ? s : -1e30f;
        }
        float p = exp2f(s);                           // unnormalized prob (log2 domain)
        p_lds[(w * 16 + quad * 4 + r) * KST + ns * 16 + ln] = f2bf(p);
      }
    }
    // P is wave-private LDS; per-wave LDS ops are in-order (lgkmcnt handles deps).
    #pragma unroll
    for (int kk = 0; kk < 64; kk += 32) {
      s16x8 pf = *(const s16x8*)&p_lds[(w * 16 + ln) * KST + kk + quad * 8];
      MFMA(acc_l, pf, ones);                          // row-sum l, no shuffles
      #pragma unroll
      for (int nt = 0; nt < 4; ++nt) {
        s16x8 vf = *(const s16x8*)&v_lds[(nt * 16 + ln) * VST + ct * 64 + kk + quad * 8];
        MFMA(acc_o[nt], pf, vf);
      }
    }
    asm volatile("" ::: "memory");  // keep next iter's P writes after this PV's reads
  }

  const int base = qt + 2 * g * (g - 1) + rq * g;     // packed chunk-slab index
  const size_t slab0 = (size_t)bz * 144 + base;
  unsigned short* op = opart + (slab0 + c) * 4096;
  #pragma unroll
  for (int nt = 0; nt < 4; ++nt)
    #pragma unroll
    for (int r = 0; r < 4; ++r)
      op[(w * 16 + quad * 4 + r) * 64 + nt * 16 + ln] = f2bf(acc_o[nt][r]);
  if (ln == 0) {
    float* lp = ml + (slab0 + c) * 64;
    #pragma unroll
    for (int r = 0; r < 4; ++r)
      lp[w * 16 + quad * 4 + r] = acc_l[r];
  }

  // ---- last-arriver combine (threadFenceReduction pattern) ----
  __threadfence();                 // make partials visible device-wide
  __syncthreads();                 // all threads' stores precede the ticket
  if (tid == 0)
    is_last = (atomicAdd(&cnt[bz * 32 + qt], 1) == nch - 1);
  __syncthreads();
  if (!is_last) return;
  __threadfence();                 // acquire side

  const int row = tid >> 2;        // 0..63
  const int ds  = (tid & 3) * 16;
  float L = 0.f;
  float acc[16];
  #pragma unroll
  for (int j = 0; j < 16; ++j) acc[j] = 0.f;
  #pragma unroll 8
  for (int ch = 0; ch < nch; ++ch) {
    L += ml[(slab0 + ch) * 64 + row];
    const unsigned short* opc = opart + (slab0 + ch) * 4096 + row * 64 + ds;
    i32x4 v0 = *(const i32x4*)(opc);
    i32x4 v1 = *(const i32x4*)(opc + 8);
    #pragma unroll
    for (int j = 0; j < 4; ++j) {
      unsigned int u0 = (unsigned int)v0[j], u1 = (unsigned int)v1[j];
      acc[j * 2]         += __uint_as_float(u0 << 16);
      acc[j * 2 + 1]     += __uint_as_float(u0 & 0xffff0000u);
      acc[8 + j * 2]     += __uint_as_float(u1 << 16);
      acc[8 + j * 2 + 1] += __uint_as_float(u1 & 0xffff0000u);
    }
  }
  float inv = 1.0f / L;
  float* o = out + ((size_t)bz * TT + qt * 64 + row) * 64 + ds;
  #pragma unroll
  for (int j = 0; j < 16; ++j) o[j] = acc[j] * inv;
}

extern "C" void kernel_launch(void* const* d_in, const int* in_sizes, int n_in,
                              void* d_out, int out_size, void* d_ws, size_t ws_size,
                              hipStream_t stream) {
  const float* x  = (const float*)d_in[0];
  const float* wq = (const float*)d_in[1];
  const float* wk = (const float*)d_in[2];
  const float* wv = (const float*)d_in[3];
  float* out = (float*)d_out;

  char* ws = (char*)d_ws;
  unsigned short* wt    = (unsigned short*)(ws + WS_WT);
  unsigned short* qkvqk = (unsigned short*)(ws + WS_QK);
  unsigned short* vt    = (unsigned short*)(ws + WS_VT);
  unsigned short* opart = (unsigned short*)(ws + WS_OP);
  float*          ml    = (float*)(ws + WS_ML);
  int*            cnt   = (int*)(ws + WS_CNT);

  pack_w_kernel<<<(192 * DM + 255) / 256, 256, 0, stream>>>(wq, wk, wv, wt, cnt);
  qkv_gemm_kernel<<<NB * TT / 32, 256, 0, stream>>>(x, wt, qkvqk, vt);
  attn_part_kernel<<<NB * 144, 256, 0, stream>>>(qkvqk, vt, opart, ml, cnt, out);
}

// Round 9
// 144.408 us; speedup vs baseline: 2.5121x; 2.5121x over previous
//
#include <hip/hip_runtime.h>

// B=8, T=2048, D_MODEL=1024, D_HEAD=64, fp32 in/out.
// pack  -> Wt bf16[192][1024]
// gemm  -> qkvqk bf16[16384][128] (Q log2-scaled | K), vT bf16[8][64][2048]
//          (m97-style: global_load_lds staging, XOR-swizzled LDS, 2-barrier K-loop)
// attn  -> split-K no-max log2 flash; 128-row q-SUPERTILE per block (2 q-tiles share
//          one 256-key K/V staging) -> bf16 partial O + f32 l per (qt, chunk)
// combine -> weight-1 merge of <=8 chunks per (b, 64-row q-tile)
#define TT   2048
#define DM   1024
#define DH   64
#define NB   8
#define KST  72    // k_lds / p_lds row stride (elems): 36 dwords = 4 mod 32 banks
#define VST  264   // v_lds row stride: 132 dwords = 4 mod 32 banks

typedef __attribute__((ext_vector_type(4))) float          f32x4;
typedef __attribute__((ext_vector_type(4))) int            i32x4;
typedef __attribute__((ext_vector_type(4))) unsigned short u16x4;
typedef __attribute__((ext_vector_type(8))) short          s16x8;  // bf16x8 frag (4 VGPRs)

__device__ __forceinline__ unsigned short f2bf(float f) {  // RNE fp32->bf16
  unsigned int u = __float_as_uint(f);
  u += 0x7fffu + ((u >> 16) & 1u);
  return (unsigned short)(u >> 16);
}

#define MFMA(acc, a, b) \
  (acc) = __builtin_amdgcn_mfma_f32_16x16x32_bf16((a), (b), (acc), 0, 0, 0)

// Async global->LDS DMA, 16B/lane. LDS dest is wave-uniform base + lane*16.
__device__ __forceinline__ void gload_lds16(const void* g, void* l) {
  __builtin_amdgcn_global_load_lds(
      (const __attribute__((address_space(1))) void*)g,
      (__attribute__((address_space(3))) void*)l, 16, 0, 0);
}

// ws layout (bytes)
#define WS_WT    0u
#define WS_QK    393216u     // 16384*128*2 = 4,194,304
#define WS_VT    4587520u    // 8*64*2048*2 = 2,097,152
#define WS_OP    6684672u    // 8*144*4096*2 = 9,437,184 (bf16 partial O)
#define WS_ML    16121856u   // 8*144*64*4  = 294,912   (f32 l per row)

// ---------------- pack: W_Q|W_K|W_V fp32[1024][64] -> Wt bf16[192][1024] -------------
__global__ __launch_bounds__(256) void pack_w_kernel(
    const float* __restrict__ wq, const float* __restrict__ wk,
    const float* __restrict__ wv, unsigned short* __restrict__ wt) {
  int idx = blockIdx.x * 256 + threadIdx.x;
  if (idx >= 192 * DM) return;
  int n = idx >> 10;
  int k = idx & (DM - 1);
  const float* src = (n < 64) ? wq : ((n < 128) ? wk : wv);
  wt[(size_t)n * DM + k] = f2bf(src[(size_t)k * DH + (n & 63)]);
}

// ---------------- QKV GEMM (m97 structure, unchanged from R6) ------------------------
__global__ __launch_bounds__(256) void qkv_gemm_kernel(
    const float* __restrict__ x, const unsigned short* __restrict__ wt,
    unsigned short* __restrict__ qkvqk, unsigned short* __restrict__ vt) {
  __shared__ __align__(16) float          a_lds[32 * 64];    // 8 KB, swizzled chunks
  __shared__ __align__(16) unsigned short b_lds[192 * 64];   // 24 KB, swizzled chunks

  const int tid  = threadIdx.x;
  const int lane = tid & 63;
  const int w    = tid >> 6;
  const int ln   = lane & 15;
  const int quad = lane >> 4;
  const int mw   = w & 1;
  const int nw   = w >> 1;
  const int m0   = blockIdx.x * 32;
  const int n0   = nw * 96;
  const int lsw  = ln & 7;          // read-side swizzle key

  int agoff[2];
  #pragma unroll
  for (int i = 0; i < 2; ++i) {
    int s = i * 256 + w * 64 + lane;
    int m = s >> 4, cc = s & 15;                 // A: 16 chunks/row (16B = 4 fp32)
    agoff[i] = (m0 + m) * DM + ((cc ^ (m & 7)) << 2);
  }
  int bgoff[6];
  #pragma unroll
  for (int j = 0; j < 6; ++j) {
    int s = j * 256 + w * 64 + lane;
    int n = s >> 3, cc = s & 7;                  // B: 8 chunks/row (16B = 8 bf16)
    bgoff[j] = n * DM + ((cc ^ (n & 7)) << 3);
  }

  f32x4 acc[6];
  #pragma unroll
  for (int i = 0; i < 6; ++i) acc[i] = (f32x4){0.f, 0.f, 0.f, 0.f};
  union { s16x8 v; unsigned short h[8]; } ap;

  #pragma unroll
  for (int i = 0; i < 2; ++i)
    gload_lds16(x + agoff[i], (void*)(a_lds + (i * 256 + w * 64) * 4));
  #pragma unroll
  for (int j = 0; j < 6; ++j)
    gload_lds16(wt + bgoff[j], (void*)(b_lds + (j * 256 + w * 64) * 8));

  for (int k0 = 0; k0 < DM; k0 += 64) {
    __syncthreads();               // drains vmcnt(0): staged tile visible
    #pragma unroll
    for (int ks = 0; ks < 64; ks += 32) {
      const int m  = mw * 16 + ln;
      const int c0 = (ks >> 2) + 2 * quad;       // float-chunk of A fragment
      f32x4 v0 = *(const f32x4*)&a_lds[m * 64 + ((c0 ^ lsw) << 2)];
      f32x4 v1 = *(const f32x4*)&a_lds[m * 64 + (((c0 + 1) ^ lsw) << 2)];
      #pragma unroll
      for (int j = 0; j < 4; ++j) { ap.h[j] = f2bf(v0[j]); ap.h[4 + j] = f2bf(v1[j]); }
      s16x8 af = ap.v;
      const int cb = (ks >> 3) + quad;           // bf16-chunk of B fragment
      #pragma unroll
      for (int nt = 0; nt < 6; ++nt) {
        int n = n0 + nt * 16 + ln;
        s16x8 bf = *(const s16x8*)&b_lds[n * 64 + ((cb ^ lsw) << 3)];
        MFMA(acc[nt], af, bf);
      }
    }
    __syncthreads();               // all waves done reading before re-stage
    if (k0 + 64 < DM) {
      const int kn = k0 + 64;
      #pragma unroll
      for (int i = 0; i < 2; ++i)
        gload_lds16(x + agoff[i] + kn, (void*)(a_lds + (i * 256 + w * 64) * 4));
      #pragma unroll
      for (int j = 0; j < 6; ++j)
        gload_lds16(wt + bgoff[j] + kn, (void*)(b_lds + (j * 256 + w * 64) * 8));
    }
  }

  const float QS = 0.18033688011112042f;  // (1/8) * log2(e)
  const int mm0 = m0 + mw * 16;
  const int bz  = mm0 >> 11;
  const int tb  = (mm0 & 2047) + quad * 4;
  #pragma unroll
  for (int nt = 0; nt < 6; ++nt) {
    const int ncol = n0 + nt * 16 + ln;
    if (ncol < 128) {                     // Q (scaled) | K -> qkvqk
      const float sc = (ncol < 64) ? QS : 1.0f;
      #pragma unroll
      for (int r = 0; r < 4; ++r) {
        int row = mm0 + quad * 4 + r;     // C/D: row = quad*4+reg, col = lane&15
        qkvqk[(size_t)row * 128 + ncol] = f2bf(acc[nt][r] * sc);
      }
    } else {                              // V -> vT[b][d][t]
      int d = ncol - 128;
      u16x4 h;
      #pragma unroll
      for (int r = 0; r < 4; ++r) h[r] = f2bf(acc[nt][r]);
      *(u16x4*)(vt + ((size_t)bz * 64 + d) * TT + tb) = h;
    }
  }
}

// ---------------- attn partial: 128-row q-supertile x 256-key chunk ------------------
// 576 jobs = 8 batches x 72 (supertile s in 0..15 has ceil((s+1)/2) chunks). One K/V
// staging serves BOTH 64-row q-tiles (qtA=2s, qtB=2s+1). No-max log2 softmax; row-sum
// via ones-MFMA. Partials keyed by (qt, chunk) exactly as before -> combine unchanged.
__global__ __launch_bounds__(256) void attn_part_kernel(
    const unsigned short* __restrict__ qkvqk, const unsigned short* __restrict__ vt,
    unsigned short* __restrict__ opart, float* __restrict__ ml) {
  // cumulative chunk counts per supertile: C[s] = sum_{u<s} (u+2)>>1
  const int Ctab[16] = {0,1,2,4,6,9,12,16,20,25,30,36,42,49,56,64};
  const int f  = blockIdx.x;       // 0..575
  const int bz = f / 72;
  const int rw = f - bz * 72;
  int s = 0;
  #pragma unroll
  for (int t = 1; t < 16; ++t) if (rw >= Ctab[t]) s = t;
  const int c = rw - Ctab[s];
  const int ntiles = min(4, 2 * s + 2 - 4 * c);   // in {2,4}
  const int qtA = 2 * s, qtB = 2 * s + 1;

  __shared__ __align__(16) unsigned short k_lds[256 * KST];
  __shared__ __align__(16) unsigned short v_lds[64 * VST];
  __shared__ __align__(16) unsigned short p_lds[64 * KST];

  const int tid  = threadIdx.x;
  const int w    = tid >> 6;
  const int lane = tid & 63;
  const int ln   = lane & 15;
  const int quad = lane >> 4;
  const int bb   = bz * TT;
  const int kbase = c * 256;

  // stage K rows [kbase, kbase+ntiles*64)
  for (int i = 0; i < 2 * ntiles; ++i) {
    int cid = i * 256 + tid;
    int row = cid >> 3, dc = (cid & 7) * 8;
    *(i32x4*)&k_lds[row * KST + dc] =
        *(const i32x4*)(qkvqk + (size_t)(bb + kbase + row) * 128 + 64 + dc);
  }
  // stage V^T cols [kbase, kbase+ntiles*64): chunks-of-8 per d-row = ntiles*8
  const int cm = ntiles * 8 - 1;               // 15 or 31
  const int dshift = (ntiles == 4) ? 5 : 4;
  for (int i = 0; i < 2 * ntiles; ++i) {
    int cid = i * 256 + tid;
    int d = cid >> dshift, tc = (cid & cm) * 8;
    *(i32x4*)&v_lds[d * VST + tc] =
        *(const i32x4*)(vt + ((size_t)bz * 64 + d) * TT + kbase + tc);
  }

  // Q fragments for both q-tiles (log2-scaled already); A-layout m=lane&15, k=quad*8+j
  const unsigned short* qrowA = qkvqk + (size_t)(bb + qtA * 64 + w * 16 + ln) * 128;
  const unsigned short* qrowB = qrowA + 64 * 128;
  const s16x8 qfA0 = *(const s16x8*)(qrowA + quad * 8);
  const s16x8 qfA1 = *(const s16x8*)(qrowA + 32 + quad * 8);
  const s16x8 qfB0 = *(const s16x8*)(qrowB + quad * 8);
  const s16x8 qfB1 = *(const s16x8*)(qrowB + 32 + quad * 8);

  s16x8 ones;
  #pragma unroll
  for (int j = 0; j < 8; ++j) ones[j] = (short)0x3F80;  // bf16 1.0

  f32x4 acc_oA[4], acc_oB[4], acc_lA, acc_lB;
  #pragma unroll
  for (int i = 0; i < 4; ++i) {
    acc_oA[i] = (f32x4){0.f, 0.f, 0.f, 0.f};
    acc_oB[i] = (f32x4){0.f, 0.f, 0.f, 0.f};
  }
  acc_lA = (f32x4){0.f, 0.f, 0.f, 0.f};
  acc_lB = (f32x4){0.f, 0.f, 0.f, 0.f};

  const int qgA = qtA * 64 + w * 16 + quad * 4;
  const int qgB = qgA + 64;
  __syncthreads();  // staging complete (single barrier in the kernel)

  for (int ct = 0; ct < ntiles; ++ct) {
    const int ktg = c * 4 + ct;

    // ---------- q-tile A pass (skip if tile entirely above the diagonal) ----------
    if (ktg <= qtA) {
      const bool diag = (ktg == qtA);
      f32x4 acc_s[4];
      #pragma unroll
      for (int i = 0; i < 4; ++i) acc_s[i] = (f32x4){0.f, 0.f, 0.f, 0.f};
      #pragma unroll
      for (int ns = 0; ns < 4; ++ns) {
        s16x8 kf0 = *(const s16x8*)&k_lds[(ct * 64 + ns * 16 + ln) * KST + quad * 8];
        s16x8 kf1 = *(const s16x8*)&k_lds[(ct * 64 + ns * 16 + ln) * KST + 32 + quad * 8];
        MFMA(acc_s[ns], qfA0, kf0);
        MFMA(acc_s[ns], qfA1, kf1);
      }
      #pragma unroll
      for (int r = 0; r < 4; ++r) {
        const int qg = qgA + r;
        #pragma unroll
        for (int ns = 0; ns < 4; ++ns) {
          float sv = acc_s[ns][r];
          if (diag) {
            int kg = ktg * 64 + ns * 16 + ln;
            sv = (kg <= qg) ? sv : -1e30f;
          }
          p_lds[(w * 16 + quad * 4 + r) * KST + ns * 16 + ln] = f2bf(exp2f(sv));
        }
      }
      #pragma unroll
      for (int kk = 0; kk < 64; kk += 32) {
        s16x8 pf = *(const s16x8*)&p_lds[(w * 16 + ln) * KST + kk + quad * 8];
        MFMA(acc_lA, pf, ones);
        #pragma unroll
        for (int nt = 0; nt < 4; ++nt) {
          s16x8 vf = *(const s16x8*)&v_lds[(nt * 16 + ln) * VST + ct * 64 + kk + quad * 8];
          MFMA(acc_oA[nt], pf, vf);
        }
      }
      asm volatile("" ::: "memory");
    }

    // ---------- q-tile B pass (always: ktg <= 2s+1 = qtB by construction) ----------
    {
      const bool diag = (ktg == qtB);
      f32x4 acc_s[4];
      #pragma unroll
      for (int i = 0; i < 4; ++i) acc_s[i] = (f32x4){0.f, 0.f, 0.f, 0.f};
      #pragma unroll
      for (int ns = 0; ns < 4; ++ns) {
        s16x8 kf0 = *(const s16x8*)&k_lds[(ct * 64 + ns * 16 + ln) * KST + quad * 8];
        s16x8 kf1 = *(const s16x8*)&k_lds[(ct * 64 + ns * 16 + ln) * KST + 32 + quad * 8];
        MFMA(acc_s[ns], qfB0, kf0);
        MFMA(acc_s[ns], qfB1, kf1);
      }
      #pragma unroll
      for (int r = 0; r < 4; ++r) {
        const int qg = qgB + r;
        #pragma unroll
        for (int ns = 0; ns < 4; ++ns) {
          float sv = acc_s[ns][r];
          if (diag) {
            int kg = ktg * 64 + ns * 16 + ln;
            sv = (kg <= qg) ? sv : -1e30f;
          }
          p_lds[(w * 16 + quad * 4 + r) * KST + ns * 16 + ln] = f2bf(exp2f(sv));
        }
      }
      #pragma unroll
      for (int kk = 0; kk < 64; kk += 32) {
        s16x8 pf = *(const s16x8*)&p_lds[(w * 16 + ln) * KST + kk + quad * 8];
        MFMA(acc_lB, pf, ones);
        #pragma unroll
        for (int nt = 0; nt < 4; ++nt) {
          s16x8 vf = *(const s16x8*)&v_lds[(nt * 16 + ln) * VST + ct * 64 + kk + quad * 8];
          MFMA(acc_oB[nt], pf, vf);
        }
      }
      asm volatile("" ::: "memory");
    }
  }

  // epilogue: two partial slabs, keyed by (qt, c) with base = (g+1)(2g+rq) packing
  #pragma unroll
  for (int half = 0; half < 2; ++half) {
    const int qt = (half == 0) ? qtA : qtB;
    const int g  = qt >> 2, rq = qt & 3;
    const int base = qt + 2 * g * (g - 1) + rq * g;
    const size_t slab = (size_t)bz * 144 + base + c;
    unsigned short* op = opart + slab * 4096;
    const f32x4* ao = (half == 0) ? acc_oA : acc_oB;
    const f32x4  al = (half == 0) ? acc_lA : acc_lB;
    #pragma unroll
    for (int nt = 0; nt < 4; ++nt)
      #pragma unroll
      for (int r = 0; r < 4; ++r)
        op[(w * 16 + quad * 4 + r) * 64 + nt * 16 + ln] = f2bf(ao[nt][r]);
    if (ln == 0) {
      float* lp = ml + slab * 64;
      #pragma unroll
      for (int r = 0; r < 4; ++r)
        lp[w * 16 + quad * 4 + r] = al[r];
    }
  }
}

// ---------------- combine: weight-1 merge of <=8 chunks (unchanged from R6) ----------
__global__ __launch_bounds__(256) void attn_combine_kernel(
    const unsigned short* __restrict__ opart, const float* __restrict__ ml,
    float* __restrict__ out) {
  const int qt = blockIdx.x;
  const int bz = blockIdx.y;
  const int aq = qt >> 2, rq = qt & 3;
  const int nch = aq + 1;
  const int base = qt + 2 * aq * (aq - 1) + rq * aq;
  const size_t slab0 = (size_t)bz * 144 + base;

  const int tid = threadIdx.x;
  const int row = tid >> 2;
  const int ds  = (tid & 3) * 16;

  float L = 0.f;
  float acc[16];
  #pragma unroll
  for (int j = 0; j < 16; ++j) acc[j] = 0.f;
  #pragma unroll 8
  for (int ch = 0; ch < nch; ++ch) {
    L += ml[(slab0 + ch) * 64 + row];
    const unsigned short* op = opart + (slab0 + ch) * 4096 + row * 64 + ds;
    i32x4 v0 = *(const i32x4*)(op);
    i32x4 v1 = *(const i32x4*)(op + 8);
    #pragma unroll
    for (int j = 0; j < 4; ++j) {
      unsigned int u0 = (unsigned int)v0[j], u1 = (unsigned int)v1[j];
      acc[j * 2]         += __uint_as_float(u0 << 16);
      acc[j * 2 + 1]     += __uint_as_float(u0 & 0xffff0000u);
      acc[8 + j * 2]     += __uint_as_float(u1 << 16);
      acc[8 + j * 2 + 1] += __uint_as_float(u1 & 0xffff0000u);
    }
  }
  float inv = 1.0f / L;
  float* o = out + ((size_t)bz * TT + qt * 64 + row) * 64 + ds;
  #pragma unroll
  for (int j = 0; j < 16; ++j) o[j] = acc[j] * inv;
}

extern "C" void kernel_launch(void* const* d_in, const int* in_sizes, int n_in,
                              void* d_out, int out_size, void* d_ws, size_t ws_size,
                              hipStream_t stream) {
  const float* x  = (const float*)d_in[0];
  const float* wq = (const float*)d_in[1];
  const float* wk = (const float*)d_in[2];
  const float* wv = (const float*)d_in[3];
  float* out = (float*)d_out;

  char* ws = (char*)d_ws;
  unsigned short* wt    = (unsigned short*)(ws + WS_WT);
  unsigned short* qkvqk = (unsigned short*)(ws + WS_QK);
  unsigned short* vt    = (unsigned short*)(ws + WS_VT);
  unsigned short* opart = (unsigned short*)(ws + WS_OP);
  float*          ml    = (float*)(ws + WS_ML);

  pack_w_kernel<<<(192 * DM + 255) / 256, 256, 0, stream>>>(wq, wk, wv, wt);
  qkv_gemm_kernel<<<NB * TT / 32, 256, 0, stream>>>(x, wt, qkvqk, vt);
  attn_part_kernel<<<NB * 72, 256, 0, stream>>>(qkvqk, vt, opart, ml);
  attn_combine_kernel<<<dim3(32, NB), 256, 0, stream>>>(opart, ml, out);
}

// Round 10
// 144.178 us; speedup vs baseline: 2.5162x; 1.0016x over previous
//
#include <hip/hip_runtime.h>

// B=8, T=2048, D_MODEL=1024, D_HEAD=64, fp32 in/out.
// pack  -> Wt bf16[192][1024]
// gemm  -> qkvqk bf16[16384][128] (Q log2-scaled | K), vT bf16[8][64][2048]
//          (m97-style: global_load_lds staging, XOR-swizzled LDS, 2-barrier K-loop)
// attn  -> split-K no-max log2 flash; 128-row q-supertile x 256-key chunk; K/V staged
//          via global_load_lds with XOR-swizzled GLOBAL source addressing
// combine -> weight-1 merge of <=8 chunks per (b, 64-row q-tile)
#define TT   2048
#define DM   1024
#define DH   64
#define NB   8
#define KST  72    // p_lds row stride (elems)

typedef __attribute__((ext_vector_type(4))) float          f32x4;
typedef __attribute__((ext_vector_type(4))) int            i32x4;
typedef __attribute__((ext_vector_type(4))) unsigned short u16x4;
typedef __attribute__((ext_vector_type(8))) short          s16x8;  // bf16x8 frag (4 VGPRs)

__device__ __forceinline__ unsigned short f2bf(float f) {  // RNE fp32->bf16
  unsigned int u = __float_as_uint(f);
  u += 0x7fffu + ((u >> 16) & 1u);
  return (unsigned short)(u >> 16);
}

#define MFMA(acc, a, b) \
  (acc) = __builtin_amdgcn_mfma_f32_16x16x32_bf16((a), (b), (acc), 0, 0, 0)

// Async global->LDS DMA, 16B/lane. LDS dest is wave-uniform base + lane*16.
__device__ __forceinline__ void gload_lds16(const void* g, void* l) {
  __builtin_amdgcn_global_load_lds(
      (const __attribute__((address_space(1))) void*)g,
      (__attribute__((address_space(3))) void*)l, 16, 0, 0);
}

// ws layout (bytes)
#define WS_WT    0u
#define WS_QK    393216u     // 16384*128*2 = 4,194,304
#define WS_VT    4587520u    // 8*64*2048*2 = 2,097,152
#define WS_OP    6684672u    // 8*144*4096*2 = 9,437,184 (bf16 partial O)
#define WS_ML    16121856u   // 8*144*64*4  = 294,912   (f32 l per row)

// ---------------- pack: W_Q|W_K|W_V fp32[1024][64] -> Wt bf16[192][1024] -------------
__global__ __launch_bounds__(256) void pack_w_kernel(
    const float* __restrict__ wq, const float* __restrict__ wk,
    const float* __restrict__ wv, unsigned short* __restrict__ wt) {
  int idx = blockIdx.x * 256 + threadIdx.x;
  if (idx >= 192 * DM) return;
  int n = idx >> 10;
  int k = idx & (DM - 1);
  const float* src = (n < 64) ? wq : ((n < 128) ? wk : wv);
  wt[(size_t)n * DM + k] = f2bf(src[(size_t)k * DH + (n & 63)]);
}

// ---------------- QKV GEMM (m97 structure, unchanged from R6) ------------------------
__global__ __launch_bounds__(256) void qkv_gemm_kernel(
    const float* __restrict__ x, const unsigned short* __restrict__ wt,
    unsigned short* __restrict__ qkvqk, unsigned short* __restrict__ vt) {
  __shared__ __align__(16) float          a_lds[32 * 64];    // 8 KB, swizzled chunks
  __shared__ __align__(16) unsigned short b_lds[192 * 64];   // 24 KB, swizzled chunks

  const int tid  = threadIdx.x;
  const int lane = tid & 63;
  const int w    = tid >> 6;
  const int ln   = lane & 15;
  const int quad = lane >> 4;
  const int mw   = w & 1;
  const int nw   = w >> 1;
  const int m0   = blockIdx.x * 32;
  const int n0   = nw * 96;
  const int lsw  = ln & 7;          // read-side swizzle key

  int agoff[2];
  #pragma unroll
  for (int i = 0; i < 2; ++i) {
    int s = i * 256 + w * 64 + lane;
    int m = s >> 4, cc = s & 15;                 // A: 16 chunks/row (16B = 4 fp32)
    agoff[i] = (m0 + m) * DM + ((cc ^ (m & 7)) << 2);
  }
  int bgoff[6];
  #pragma unroll
  for (int j = 0; j < 6; ++j) {
    int s = j * 256 + w * 64 + lane;
    int n = s >> 3, cc = s & 7;                  // B: 8 chunks/row (16B = 8 bf16)
    bgoff[j] = n * DM + ((cc ^ (n & 7)) << 3);
  }

  f32x4 acc[6];
  #pragma unroll
  for (int i = 0; i < 6; ++i) acc[i] = (f32x4){0.f, 0.f, 0.f, 0.f};
  union { s16x8 v; unsigned short h[8]; } ap;

  #pragma unroll
  for (int i = 0; i < 2; ++i)
    gload_lds16(x + agoff[i], (void*)(a_lds + (i * 256 + w * 64) * 4));
  #pragma unroll
  for (int j = 0; j < 6; ++j)
    gload_lds16(wt + bgoff[j], (void*)(b_lds + (j * 256 + w * 64) * 8));

  for (int k0 = 0; k0 < DM; k0 += 64) {
    __syncthreads();               // drains vmcnt(0): staged tile visible
    #pragma unroll
    for (int ks = 0; ks < 64; ks += 32) {
      const int m  = mw * 16 + ln;
      const int c0 = (ks >> 2) + 2 * quad;       // float-chunk of A fragment
      f32x4 v0 = *(const f32x4*)&a_lds[m * 64 + ((c0 ^ lsw) << 2)];
      f32x4 v1 = *(const f32x4*)&a_lds[m * 64 + (((c0 + 1) ^ lsw) << 2)];
      #pragma unroll
      for (int j = 0; j < 4; ++j) { ap.h[j] = f2bf(v0[j]); ap.h[4 + j] = f2bf(v1[j]); }
      s16x8 af = ap.v;
      const int cb = (ks >> 3) + quad;           // bf16-chunk of B fragment
      #pragma unroll
      for (int nt = 0; nt < 6; ++nt) {
        int n = n0 + nt * 16 + ln;
        s16x8 bf = *(const s16x8*)&b_lds[n * 64 + ((cb ^ lsw) << 3)];
        MFMA(acc[nt], af, bf);
      }
    }
    __syncthreads();               // all waves done reading before re-stage
    if (k0 + 64 < DM) {
      const int kn = k0 + 64;
      #pragma unroll
      for (int i = 0; i < 2; ++i)
        gload_lds16(x + agoff[i] + kn, (void*)(a_lds + (i * 256 + w * 64) * 4));
      #pragma unroll
      for (int j = 0; j < 6; ++j)
        gload_lds16(wt + bgoff[j] + kn, (void*)(b_lds + (j * 256 + w * 64) * 8));
    }
  }

  const float QS = 0.18033688011112042f;  // (1/8) * log2(e)
  const int mm0 = m0 + mw * 16;
  const int bz  = mm0 >> 11;
  const int tb  = (mm0 & 2047) + quad * 4;
  #pragma unroll
  for (int nt = 0; nt < 6; ++nt) {
    const int ncol = n0 + nt * 16 + ln;
    if (ncol < 128) {                     // Q (scaled) | K -> qkvqk
      const float sc = (ncol < 64) ? QS : 1.0f;
      #pragma unroll
      for (int r = 0; r < 4; ++r) {
        int row = mm0 + quad * 4 + r;     // C/D: row = quad*4+reg, col = lane&15
        qkvqk[(size_t)row * 128 + ncol] = f2bf(acc[nt][r] * sc);
      }
    } else {                              // V -> vT[b][d][t]
      int d = ncol - 128;
      u16x4 h;
      #pragma unroll
      for (int r = 0; r < 4; ++r) h[r] = f2bf(acc[nt][r]);
      *(u16x4*)(vt + ((size_t)bz * 64 + d) * TT + tb) = h;
    }
  }
}

// ---------------- attn partial: 128-row q-supertile x 256-key chunk ------------------
// 576 jobs = 8 batches x 72. K/V staged by global_load_lds: the XOR swizzle lives in
// the per-lane GLOBAL source address (LDS dest is the HW-native contiguous pattern);
// fragment reads un-swizzle -> 2-way bank aliasing (free). Full 256-key window always
// staged (uniform); only ntiles k-tiles computed.
__global__ __launch_bounds__(256) void attn_part_kernel(
    const unsigned short* __restrict__ qkvqk, const unsigned short* __restrict__ vt,
    unsigned short* __restrict__ opart, float* __restrict__ ml) {
  // cumulative chunk counts per supertile: C[s] = sum_{u<s} (u+2)>>1
  const int Ctab[16] = {0,1,2,4,6,9,12,16,20,25,30,36,42,49,56,64};
  const int f  = blockIdx.x;       // 0..575
  const int bz = f / 72;
  const int rw = f - bz * 72;
  int s = 0;
  #pragma unroll
  for (int t = 1; t < 16; ++t) if (rw >= Ctab[t]) s = t;
  const int c = rw - Ctab[s];
  const int ntiles = min(4, 2 * s + 2 - 4 * c);   // in {2,4}
  const int qtA = 2 * s, qtB = 2 * s + 1;

  __shared__ __align__(16) unsigned short k_lds[256 * 64];   // 32 KB, swizzled chunks
  __shared__ __align__(16) unsigned short v_lds[64 * 256];   // 32 KB, swizzled chunks
  __shared__ __align__(16) unsigned short p_lds[64 * KST];   // 9 KB, padded

  const int tid  = threadIdx.x;
  const int w    = tid >> 6;
  const int lane = tid & 63;
  const int ln   = lane & 15;
  const int quad = lane >> 4;
  const int lsw  = ln & 7;         // read-side swizzle key
  const int bb   = bz * TT;
  const int kbase = c * 256;

  // ---- stage K: 2048 chunk-slots; slot s -> (row=s>>3, cc=s&7); data = cc ^ (row&7)
  #pragma unroll
  for (int i = 0; i < 8; ++i) {
    int base = (i * 4 + w) * 64;
    int slot = base + lane;
    int row = slot >> 3, cc = slot & 7;
    gload_lds16(qkvqk + (size_t)(bb + kbase + row) * 128 + 64 + ((cc ^ (row & 7)) << 3),
                (void*)(k_lds + base * 8));
  }
  // ---- stage V^T: 2048 chunk-slots; slot -> (d=s>>5, cc=s&31); data = cc ^ (d&7)
  #pragma unroll
  for (int i = 0; i < 8; ++i) {
    int base = (i * 4 + w) * 64;
    int slot = base + lane;
    int d = slot >> 5, cc = slot & 31;
    gload_lds16(vt + ((size_t)bz * 64 + d) * TT + kbase + ((cc ^ (d & 7)) << 3),
                (void*)(v_lds + base * 8));
  }

  // Q fragments for both q-tiles (log2-scaled already); A-layout m=lane&15, k=quad*8+j
  const unsigned short* qrowA = qkvqk + (size_t)(bb + qtA * 64 + w * 16 + ln) * 128;
  const unsigned short* qrowB = qrowA + 64 * 128;
  const s16x8 qfA0 = *(const s16x8*)(qrowA + quad * 8);
  const s16x8 qfA1 = *(const s16x8*)(qrowA + 32 + quad * 8);
  const s16x8 qfB0 = *(const s16x8*)(qrowB + quad * 8);
  const s16x8 qfB1 = *(const s16x8*)(qrowB + 32 + quad * 8);

  s16x8 ones;
  #pragma unroll
  for (int j = 0; j < 8; ++j) ones[j] = (short)0x3F80;  // bf16 1.0

  f32x4 acc_oA[4], acc_oB[4], acc_lA, acc_lB;
  #pragma unroll
  for (int i = 0; i < 4; ++i) {
    acc_oA[i] = (f32x4){0.f, 0.f, 0.f, 0.f};
    acc_oB[i] = (f32x4){0.f, 0.f, 0.f, 0.f};
  }
  acc_lA = (f32x4){0.f, 0.f, 0.f, 0.f};
  acc_lB = (f32x4){0.f, 0.f, 0.f, 0.f};

  const int qgA = qtA * 64 + w * 16 + quad * 4;
  const int qgB = qgA + 64;
  __syncthreads();  // drains vmcnt(0): K/V staged

  for (int ct = 0; ct < ntiles; ++ct) {
    const int ktg = c * 4 + ct;
    // K fragment chunk indices for kk=0,32 (un-swizzled with ^lsw at read)
    const int kc0 = quad;          // kk=0  -> chunk (0>>3)+quad
    const int kc1 = 4 + quad;      // kk=32 -> chunk (32>>3)+quad

    // ---------- q-tile A pass (skip if tile entirely above the diagonal) ----------
    if (ktg <= qtA) {
      const bool diag = (ktg == qtA);
      f32x4 acc_s[4];
      #pragma unroll
      for (int i = 0; i < 4; ++i) acc_s[i] = (f32x4){0.f, 0.f, 0.f, 0.f};
      #pragma unroll
      for (int ns = 0; ns < 4; ++ns) {
        const int krow = ct * 64 + ns * 16 + ln;
        s16x8 kf0 = *(const s16x8*)&k_lds[krow * 64 + ((kc0 ^ lsw) << 3)];
        s16x8 kf1 = *(const s16x8*)&k_lds[krow * 64 + ((kc1 ^ lsw) << 3)];
        MFMA(acc_s[ns], qfA0, kf0);
        MFMA(acc_s[ns], qfA1, kf1);
      }
      #pragma unroll
      for (int r = 0; r < 4; ++r) {
        const int qg = qgA + r;
        #pragma unroll
        for (int ns = 0; ns < 4; ++ns) {
          float sv = acc_s[ns][r];
          if (diag) {
            int kg = ktg * 64 + ns * 16 + ln;
            sv = (kg <= qg) ? sv : -1e30f;
          }
          p_lds[(w * 16 + quad * 4 + r) * KST + ns * 16 + ln] = f2bf(exp2f(sv));
        }
      }
      #pragma unroll
      for (int kk = 0; kk < 64; kk += 32) {
        s16x8 pf = *(const s16x8*)&p_lds[(w * 16 + ln) * KST + kk + quad * 8];
        MFMA(acc_lA, pf, ones);
        #pragma unroll
        for (int nt = 0; nt < 4; ++nt) {
          const int d  = nt * 16 + ln;
          const int sc = ct * 8 + (((kk >> 3) + quad) ^ lsw);
          s16x8 vf = *(const s16x8*)&v_lds[d * 256 + sc * 8];
          MFMA(acc_oA[nt], pf, vf);
        }
      }
      asm volatile("" ::: "memory");
    }

    // ---------- q-tile B pass (always: ktg <= 2s+1 = qtB by construction) ----------
    {
      const bool diag = (ktg == qtB);
      f32x4 acc_s[4];
      #pragma unroll
      for (int i = 0; i < 4; ++i) acc_s[i] = (f32x4){0.f, 0.f, 0.f, 0.f};
      #pragma unroll
      for (int ns = 0; ns < 4; ++ns) {
        const int krow = ct * 64 + ns * 16 + ln;
        s16x8 kf0 = *(const s16x8*)&k_lds[krow * 64 + ((kc0 ^ lsw) << 3)];
        s16x8 kf1 = *(const s16x8*)&k_lds[krow * 64 + ((kc1 ^ lsw) << 3)];
        MFMA(acc_s[ns], qfB0, kf0);
        MFMA(acc_s[ns], qfB1, kf1);
      }
      #pragma unroll
      for (int r = 0; r < 4; ++r) {
        const int qg = qgB + r;
        #pragma unroll
        for (int ns = 0; ns < 4; ++ns) {
          float sv = acc_s[ns][r];
          if (diag) {
            int kg = ktg * 64 + ns * 16 + ln;
            sv = (kg <= qg) ? sv : -1e30f;
          }
          p_lds[(w * 16 + quad * 4 + r) * KST + ns * 16 + ln] = f2bf(exp2f(sv));
        }
      }
      #pragma unroll
      for (int kk = 0; kk < 64; kk += 32) {
        s16x8 pf = *(const s16x8*)&p_lds[(w * 16 + ln) * KST + kk + quad * 8];
        MFMA(acc_lB, pf, ones);
        #pragma unroll
        for (int nt = 0; nt < 4; ++nt) {
          const int d  = nt * 16 + ln;
          const int sc = ct * 8 + (((kk >> 3) + quad) ^ lsw);
          s16x8 vf = *(const s16x8*)&v_lds[d * 256 + sc * 8];
          MFMA(acc_oB[nt], pf, vf);
        }
      }
      asm volatile("" ::: "memory");
    }
  }

  // epilogue: two partial slabs, keyed by (qt, c) with base = qt + 2g(g-1) + rq*g
  #pragma unroll
  for (int half = 0; half < 2; ++half) {
    const int qt = (half == 0) ? qtA : qtB;
    const int g  = qt >> 2, rq = qt & 3;
    const int base = qt + 2 * g * (g - 1) + rq * g;
    const size_t slab = (size_t)bz * 144 + base + c;
    unsigned short* op = opart + slab * 4096;
    const f32x4* ao = (half == 0) ? acc_oA : acc_oB;
    const f32x4  al = (half == 0) ? acc_lA : acc_lB;
    #pragma unroll
    for (int nt = 0; nt < 4; ++nt)
      #pragma unroll
      for (int r = 0; r < 4; ++r)
        op[(w * 16 + quad * 4 + r) * 64 + nt * 16 + ln] = f2bf(ao[nt][r]);
    if (ln == 0) {
      float* lp = ml + slab * 64;
      #pragma unroll
      for (int r = 0; r < 4; ++r)
        lp[w * 16 + quad * 4 + r] = al[r];
    }
  }
}

// ---------------- combine: weight-1 merge of <=8 chunks (unchanged) ------------------
__global__ __launch_bounds__(256) void attn_combine_kernel(
    const unsigned short* __restrict__ opart, const float* __restrict__ ml,
    float* __restrict__ out) {
  const int qt = blockIdx.x;
  const int bz = blockIdx.y;
  const int aq = qt >> 2, rq = qt & 3;
  const int nch = aq + 1;
  const int base = qt + 2 * aq * (aq - 1) + rq * aq;
  const size_t slab0 = (size_t)bz * 144 + base;

  const int tid = threadIdx.x;
  const int row = tid >> 2;
  const int ds  = (tid & 3) * 16;

  float L = 0.f;
  float acc[16];
  #pragma unroll
  for (int j = 0; j < 16; ++j) acc[j] = 0.f;
  #pragma unroll 8
  for (int ch = 0; ch < nch; ++ch) {
    L += ml[(slab0 + ch) * 64 + row];
    const unsigned short* op = opart + (slab0 + ch) * 4096 + row * 64 + ds;
    i32x4 v0 = *(const i32x4*)(op);
    i32x4 v1 = *(const i32x4*)(op + 8);
    #pragma unroll
    for (int j = 0; j < 4; ++j) {
      unsigned int u0 = (unsigned int)v0[j], u1 = (unsigned int)v1[j];
      acc[j * 2]         += __uint_as_float(u0 << 16);
      acc[j * 2 + 1]     += __uint_as_float(u0 & 0xffff0000u);
      acc[8 + j * 2]     += __uint_as_float(u1 << 16);
      acc[8 + j * 2 + 1] += __uint_as_float(u1 & 0xffff0000u);
    }
  }
  float inv = 1.0f / L;
  float* o = out + ((size_t)bz * TT + qt * 64 + row) * 64 + ds;
  #pragma unroll
  for (int j = 0; j < 16; ++j) o[j] = acc[j] * inv;
}

extern "C" void kernel_launch(void* const* d_in, const int* in_sizes, int n_in,
                              void* d_out, int out_size, void* d_ws, size_t ws_size,
                              hipStream_t stream) {
  const float* x  = (const float*)d_in[0];
  const float* wq = (const float*)d_in[1];
  const float* wk = (const float*)d_in[2];
  const float* wv = (const float*)d_in[3];
  float* out = (float*)d_out;

  char* ws = (char*)d_ws;
  unsigned short* wt    = (unsigned short*)(ws + WS_WT);
  unsigned short* qkvqk = (unsigned short*)(ws + WS_QK);
  unsigned short* vt    = (unsigned short*)(ws + WS_VT);
  unsigned short* opart = (unsigned short*)(ws + WS_OP);
  float*          ml    = (float*)(ws + WS_ML);

  pack_w_kernel<<<(192 * DM + 255) / 256, 256, 0, stream>>>(wq, wk, wv, wt);
  qkv_gemm_kernel<<<NB * TT / 32, 256, 0, stream>>>(x, wt, qkvqk, vt);
  attn_part_kernel<<<NB * 72, 256, 0, stream>>>(qkvqk, vt, opart, ml);
  attn_combine_kernel<<<dim3(32, NB), 256, 0, stream>>>(opart, ml, out);
}